// Round 9
// baseline (89.853 us; speedup 1.0000x reference)
//
#include <hip/hip_runtime.h>
#include <hip/hip_bf16.h>
#include <math.h>

typedef unsigned int uint32;
typedef __attribute__((ext_vector_type(8))) short s8v;
typedef __attribute__((ext_vector_type(4))) float f4v;

// Problem constants
#define LH 4
#define RH 4
#define DD 64
#define BB 2
#define TT 96
#define NTOK (BB*TT)           // 192
#define HEADS 16
#define VHEADS 10              // heads with r <= l
#define INV_H 0.0625f
#define NI 2                   // query tokens per wave
#define ZBLK 96                // zerofill blocks appended to pdense_qkv

struct U2 { uint32 x, y; };
struct U4 { uint32 x, y, z, w; };

__device__ __forceinline__ uint32 f2bf(float f) {
    return (uint32)__builtin_bit_cast(unsigned short, __float2bfloat16(f));
}
__device__ __forceinline__ uint32 pkbf(float lo, float hi) {
    return f2bf(lo) | (f2bf(hi) << 16);
}

// ---------------------------------------------------------------------------
// PartialDense body: Y[:, c0:c0+32) = (Wr^T (X Wc) + b)*scale, one token,
// one 32-column half. 128 threads: thread (g4 = a/i quad, cq = c quad in half)
// computes a 4x4 output tile per pass.
// MODE: 0 = fp32 merged [t][a][c]; 1 = bf16 separated [bh][t][p*16+m];
//       2 = bf16 separated TRANSPOSED [bh][t][u'*16+m]  (for V)
// ---------------------------------------------------------------------------
template<int MODE>
__device__ __forceinline__ void pdense_body(
    const float* __restrict__ Xp,
    const float* __restrict__ Wr, const float* __restrict__ Wc,
    const float* __restrict__ bias, void* __restrict__ dstv,
    float scale, int token, int half)
{
    __shared__ float XsT[64 * 68];   // X transposed: XsT[j*68 + i]
    __shared__ float T1r[64 * 36];   // T1 half: T1r[i*36 + clocal]

    const int tid = threadIdx.x;     // 0..127
    const int g4 = tid >> 3;         // 0..15 (a/i quad)
    const int cq = tid & 7;          // 0..7  (c quad within half)
    const int c0 = half * 32 + cq * 4;

    #pragma unroll
    for (int rep = 0; rep < 32; ++rep) {
        int idx = tid + rep * 128;   // = i*64 + j
        int i = idx >> 6, j = idx & 63;
        XsT[j * 68 + i] = Xp[idx];
    }
    __syncthreads();

    // pass 1: T1[i][c] = sum_j X[i][j] * Wc[j][c]
    {
        const float4* X4 = (const float4*)XsT;
        float4 a0 = {0,0,0,0}, a1 = {0,0,0,0}, a2 = {0,0,0,0}, a3 = {0,0,0,0};
        #pragma unroll 8
        for (int j = 0; j < 64; ++j) {
            float4 xv = X4[j * 17 + g4];
            float4 wv = *(const float4*)&Wc[j * 64 + c0];
            a0.x = fmaf(xv.x, wv.x, a0.x); a0.y = fmaf(xv.x, wv.y, a0.y);
            a0.z = fmaf(xv.x, wv.z, a0.z); a0.w = fmaf(xv.x, wv.w, a0.w);
            a1.x = fmaf(xv.y, wv.x, a1.x); a1.y = fmaf(xv.y, wv.y, a1.y);
            a1.z = fmaf(xv.y, wv.z, a1.z); a1.w = fmaf(xv.y, wv.w, a1.w);
            a2.x = fmaf(xv.z, wv.x, a2.x); a2.y = fmaf(xv.z, wv.y, a2.y);
            a2.z = fmaf(xv.z, wv.z, a2.z); a2.w = fmaf(xv.z, wv.w, a2.w);
            a3.x = fmaf(xv.w, wv.x, a3.x); a3.y = fmaf(xv.w, wv.y, a3.y);
            a3.z = fmaf(xv.w, wv.z, a3.z); a3.w = fmaf(xv.w, wv.w, a3.w);
        }
        *(float4*)&T1r[(g4 * 4 + 0) * 36 + cq * 4] = a0;
        *(float4*)&T1r[(g4 * 4 + 1) * 36 + cq * 4] = a1;
        *(float4*)&T1r[(g4 * 4 + 2) * 36 + cq * 4] = a2;
        *(float4*)&T1r[(g4 * 4 + 3) * 36 + cq * 4] = a3;
    }
    __syncthreads();

    // pass 2: Y[a][c] = sum_i Wr[i][a] * T1[i][c]
    float4 y0 = {0,0,0,0}, y1 = {0,0,0,0}, y2 = {0,0,0,0}, y3 = {0,0,0,0};
    #pragma unroll 8
    for (int i = 0; i < 64; ++i) {
        float4 wv = *(const float4*)&Wr[i * 64 + g4 * 4];
        float4 tv = *(const float4*)&T1r[i * 36 + cq * 4];
        y0.x = fmaf(wv.x, tv.x, y0.x); y0.y = fmaf(wv.x, tv.y, y0.y);
        y0.z = fmaf(wv.x, tv.z, y0.z); y0.w = fmaf(wv.x, tv.w, y0.w);
        y1.x = fmaf(wv.y, tv.x, y1.x); y1.y = fmaf(wv.y, tv.y, y1.y);
        y1.z = fmaf(wv.y, tv.z, y1.z); y1.w = fmaf(wv.y, tv.w, y1.w);
        y2.x = fmaf(wv.z, tv.x, y2.x); y2.y = fmaf(wv.z, tv.y, y2.y);
        y2.z = fmaf(wv.z, tv.z, y2.z); y2.w = fmaf(wv.z, tv.w, y2.w);
        y3.x = fmaf(wv.w, tv.x, y3.x); y3.y = fmaf(wv.w, tv.y, y3.y);
        y3.z = fmaf(wv.w, tv.z, y3.z); y3.w = fmaf(wv.w, tv.w, y3.w);
    }

    const int bI = token / TT, t = token % TT;
    float z[4][4];
    {
        float4 ys[4] = {y0, y1, y2, y3};
        #pragma unroll
        for (int aa = 0; aa < 4; ++aa) {
            float4 bv = *(const float4*)&bias[(g4 * 4 + aa) * 64 + c0];
            z[aa][0] = (ys[aa].x + bv.x) * scale;
            z[aa][1] = (ys[aa].y + bv.y) * scale;
            z[aa][2] = (ys[aa].z + bv.z) * scale;
            z[aa][3] = (ys[aa].w + bv.w) * scale;
        }
    }

    if (MODE == 0) {
        #pragma unroll
        for (int aa = 0; aa < 4; ++aa) {
            float4 v = {z[aa][0], z[aa][1], z[aa][2], z[aa][3]};
            *(float4*)((float*)dstv + (size_t)token * 4096 + (g4 * 4 + aa) * 64 + c0) = v;
        }
    } else if (MODE == 1) {
        const int r = c0 >> 4, cc = c0 & 15;
        #pragma unroll
        for (int aa = 0; aa < 4; ++aa) {
            int a = g4 * 4 + aa, lh = a >> 4, p = a & 15;
            U2 pk = { pkbf(z[aa][0], z[aa][1]), pkbf(z[aa][2], z[aa][3]) };
            *(U2*)((unsigned short*)dstv +
                   ((size_t)((bI * HEADS + lh * RH + r) * TT + t)) * 256 + p * 16 + cc) = pk;
        }
    } else {
        // V transposed within head tile: vt[u'][m] = Y[lh*16+m][r*16+u']
        const int a0i = g4 * 4;
        const int lh = a0i >> 4, m0 = a0i & 15;
        #pragma unroll
        for (int cc2 = 0; cc2 < 4; ++cc2) {
            int cfull = c0 + cc2, r = cfull >> 4, up = cfull & 15;
            U2 pk = { pkbf(z[0][cc2], z[1][cc2]), pkbf(z[2][cc2], z[3][cc2]) };
            *(U2*)((unsigned short*)dstv +
                   ((size_t)((bI * HEADS + lh * RH + r) * TT + t)) * 256 + up * 16 + m0) = pk;
        }
    }
}

// Fused q/k/v projection (+ att zerofill tail blocks)
__global__ __launch_bounds__(128, 2) void pdense_qkv_kernel(
    const float* __restrict__ Xq, const float* __restrict__ Xk, const float* __restrict__ Xv,
    const float* __restrict__ Wq_row, const float* __restrict__ Wq_col, const float* __restrict__ bq,
    const float* __restrict__ Wk_row, const float* __restrict__ Wk_col, const float* __restrict__ bk,
    const float* __restrict__ Wv_row, const float* __restrict__ Wv_col, const float* __restrict__ bv,
    unsigned short* __restrict__ q_bf, unsigned short* __restrict__ k_bf,
    unsigned short* __restrict__ vt_bf, float* __restrict__ att)
{
    const int bid = blockIdx.x;
    if (bid >= 3 * NTOK * 2) {
        const int zb = bid - 3 * NTOK * 2;
        float4* a4 = (float4*)att;
        #pragma unroll
        for (int k = 0; k < 16; ++k)
            a4[(size_t)zb * 2048 + k * 128 + threadIdx.x] = float4{0.f, 0.f, 0.f, 0.f};
        return;
    }
    const int which = bid / (NTOK * 2);
    const int rem   = bid % (NTOK * 2);
    const int token = rem >> 1, half = rem & 1;

    if (which == 0)       // Q gets extra 1/h (folds the logits/h)
        pdense_body<1>(Xq + (size_t)token * 4096, Wq_row, Wq_col, bq, q_bf, INV_H * INV_H, token, half);
    else if (which == 1)
        pdense_body<1>(Xk + (size_t)token * 4096, Wk_row, Wk_col, bk, k_bf, INV_H, token, half);
    else
        pdense_body<2>(Xv + (size_t)token * 4096, Wv_row, Wv_col, bv, vt_bf, INV_H, token, half);
}

__global__ __launch_bounds__(128, 2) void pdense_out_kernel(
    const float* __restrict__ X, const float* __restrict__ Wr,
    const float* __restrict__ Wc, const float* __restrict__ bias,
    float* __restrict__ dst)
{
    const int token = blockIdx.x >> 1, half = blockIdx.x & 1;
    pdense_body<0>(X + (size_t)token * 4096, Wr, Wc, bias, dst, INV_H, token, half);
}

// ---------------------------------------------------------------------------
// MFMA attention, single path: mfma_f32_16x16x32_bf16 (HW-verified layouts).
// 1 wave per (batch, valid head, pair of query tokens).
// Swapped QK^T: D[u][p] = K_j . Q_i^T with K zero-padded (k>=16 lanes' B = 0).
// Pass 1: denominators (lane-local). Pass 2: recompute, normalize, pack W to
// bf16, shuffle into PV B-frag (contiguous k=8g+s), PV-accumulate.
// ---------------------------------------------------------------------------
__global__ __launch_bounds__(64, 4) void attn_kernel(
    const unsigned short* __restrict__ q_bf,
    const unsigned short* __restrict__ k_bf,
    const unsigned short* __restrict__ vt_bf,
    float* __restrict__ att)
{
    const int ip = blockIdx.x % (TT / NI);
    const int vh = (blockIdx.x / (TT / NI)) % VHEADS;
    const int bI = blockIdx.x / ((TT / NI) * VHEADS);
    const int l = (vh >= 1) + (vh >= 3) + (vh >= 6);
    const int r = vh - (l * (l + 1)) / 2;
    const int head = l * RH + r;
    const int i0 = ip * NI;
    const int lane = threadIdx.x;
    const int c = lane & 15, g = lane >> 4;

    const size_t hb = (size_t)(bI * HEADS + head) * TT * 256;
    const f4v fz = {0.f, 0.f, 0.f, 0.f};
    const s8v zz = {0, 0, 0, 0, 0, 0, 0, 0};

    // B-operand fragments (Q): lane (c,g) supplies B[k=8g+s][col=c] = Q[c][k];
    // k >= 16 (g >= 2) is zero padding.
    const int fo = c * 16 + (g & 1) * 8;
    s8v qf0 = *(const s8v*)(q_bf + hb + (size_t)(i0 + 0) * 256 + fo);
    s8v qf1 = *(const s8v*)(q_bf + hb + (size_t)(i0 + 1) * 256 + fo);
    if (g >= 2) { qf0 = zz; qf1 = zz; }
    const unsigned short* kp = k_bf + hb + fo;
    const unsigned short* vp = vt_bf + hb + fo;

    // pass 1: softmax denominators. Lane (c,g) reg t owns (p=c, u=4g+t).
    float ls0[4] = {0,0,0,0}, ls1[4] = {0,0,0,0};
    #pragma unroll 4
    for (int j = 0; j < TT; ++j) {
        s8v kf = *(const s8v*)(kp + (size_t)j * 256);
        f4v d0 = __builtin_amdgcn_mfma_f32_16x16x32_bf16(kf, qf0, fz, 0, 0, 0);
        f4v d1 = __builtin_amdgcn_mfma_f32_16x16x32_bf16(kf, qf1, fz, 0, 0, 0);
        ls0[0] += __expf(d0[0]); ls0[1] += __expf(d0[1]);
        ls0[2] += __expf(d0[2]); ls0[3] += __expf(d0[3]);
        ls1[0] += __expf(d1[0]); ls1[1] += __expf(d1[1]);
        ls1[2] += __expf(d1[2]); ls1[3] += __expf(d1[3]);
    }
    float in0[4], in1[4];
    #pragma unroll
    for (int t = 0; t < 4; ++t) { in0[t] = 1.f / ls0[t]; in1[t] = 1.f / ls1[t]; }

    // pass 2: recompute S, normalize, redistribute W into PV B-frag, PV MFMA.
    // Dest lane (c,g) needs W[p=c][u=8g..8g+7] (g<2), from source lanes
    // (c, 2g) and (c, 2g+1), regs packed as 2 uint32 each.
    const int s0 = ((2 * g) & 3) * 16 + c;
    const int s1 = ((2 * g + 1) & 3) * 16 + c;
    f4v acc0 = fz, acc1 = fz;
    #pragma unroll 2
    for (int j = 0; j < TT; ++j) {
        s8v kf = *(const s8v*)(kp + (size_t)j * 256);
        s8v vf = *(const s8v*)(vp + (size_t)j * 256);
        f4v d0 = __builtin_amdgcn_mfma_f32_16x16x32_bf16(kf, qf0, fz, 0, 0, 0);
        f4v d1 = __builtin_amdgcn_mfma_f32_16x16x32_bf16(kf, qf1, fz, 0, 0, 0);
        float w00 = __expf(d0[0]) * in0[0], w01 = __expf(d0[1]) * in0[1];
        float w02 = __expf(d0[2]) * in0[2], w03 = __expf(d0[3]) * in0[3];
        float w10 = __expf(d1[0]) * in1[0], w11 = __expf(d1[1]) * in1[1];
        float w12 = __expf(d1[2]) * in1[2], w13 = __expf(d1[3]) * in1[3];
        uint32 a0p = pkbf(w00, w01), a1p = pkbf(w02, w03);
        uint32 b0p = pkbf(w10, w11), b1p = pkbf(w12, w13);
        uint32 W0 = __shfl(a0p, s0, 64), W1 = __shfl(a1p, s0, 64);
        uint32 W2 = __shfl(a0p, s1, 64), W3 = __shfl(a1p, s1, 64);
        uint32 X0 = __shfl(b0p, s0, 64), X1 = __shfl(b1p, s0, 64);
        uint32 X2 = __shfl(b0p, s1, 64), X3 = __shfl(b1p, s1, 64);
        if (g >= 2) { W0 = W1 = W2 = W3 = 0u; X0 = X1 = X2 = X3 = 0u; }
        U4 u0 = {W0, W1, W2, W3};
        U4 u1 = {X0, X1, X2, X3};
        acc0 = __builtin_amdgcn_mfma_f32_16x16x32_bf16(vf, __builtin_bit_cast(s8v, u0), acc0, 0, 0, 0);
        acc1 = __builtin_amdgcn_mfma_f32_16x16x32_bf16(vf, __builtin_bit_cast(s8v, u1), acc1, 0, 0, 0);
    }

    // D[u'=4g+t][p=c] -> att[i][l*16+p][r*16+u'], float4 along u'
    float* op = att + ((size_t)(bI * TT + i0) * DD + (l * 16 + c)) * DD + r * 16 + g * 4;
    *(f4v*)op = acc0;
    *(f4v*)(op + 4096) = acc1;
}

// ---------------------------------------------------------------------------
extern "C" void kernel_launch(void* const* d_in, const int* in_sizes, int n_in,
                              void* d_out, int out_size, void* d_ws, size_t ws_size,
                              hipStream_t stream) {
    const float* queries = (const float*)d_in[0];
    const float* keys    = (const float*)d_in[1];
    const float* values  = (const float*)d_in[2];
    const float* Wq_row  = (const float*)d_in[3];
    const float* Wq_col  = (const float*)d_in[4];
    const float* bq      = (const float*)d_in[5];
    const float* Wk_row  = (const float*)d_in[6];
    const float* Wk_col  = (const float*)d_in[7];
    const float* bk      = (const float*)d_in[8];
    const float* Wv_row  = (const float*)d_in[9];
    const float* Wv_col  = (const float*)d_in[10];
    const float* bv      = (const float*)d_in[11];
    const float* Wo_row  = (const float*)d_in[12];
    const float* Wo_col  = (const float*)d_in[13];
    const float* bo      = (const float*)d_in[14];
    float* out = (float*)d_out;

    const size_t SEP = (size_t)BB * HEADS * TT * 256;   // 786432 elements
    unsigned short* q_bf  = (unsigned short*)d_ws;
    unsigned short* k_bf  = q_bf + SEP;
    unsigned short* vt_bf = k_bf + SEP;
    float* att = (float*)(vt_bf + SEP);                 // 16B-aligned

    pdense_qkv_kernel<<<3 * NTOK * 2 + ZBLK, 128, 0, stream>>>(
        queries, keys, values,
        Wq_row, Wq_col, bq, Wk_row, Wk_col, bk, Wv_row, Wv_col, bv,
        q_bf, k_bf, vt_bf, att);

    attn_kernel<<<BB * VHEADS * (TT / NI), 64, 0, stream>>>(q_bf, k_bf, vt_bf, att);

    pdense_out_kernel<<<NTOK * 2, 128, 0, stream>>>(att, Wo_row, Wo_col, bo, out);
}

// Round 10
// 66.510 us; speedup vs baseline: 1.3510x; 1.3510x over previous
//
#include <hip/hip_runtime.h>
#include <hip/hip_bf16.h>
#include <math.h>

typedef unsigned int uint32;
typedef __attribute__((ext_vector_type(8))) short s8v;
typedef __attribute__((ext_vector_type(16))) float f16v;
typedef __attribute__((ext_vector_type(2))) unsigned int u2v;

// Problem constants
#define LH 4
#define RH 4
#define DD 64
#define BB 2
#define TT 96
#define NTOK (BB*TT)           // 192
#define HEADS 16
#define VHEADS 10              // heads with r <= l
#define INV_H 0.0625f
#define LOG2E 1.4426950408889634f
#define ZBLK 96                // zerofill blocks appended to pdense_qkv

struct U2 { uint32 x, y; };
struct U4 { uint32 x, y, z, w; };

__device__ __forceinline__ uint32 f2bf(float f) {
    return (uint32)__builtin_bit_cast(unsigned short, __float2bfloat16(f));
}
__device__ __forceinline__ uint32 pkbf(float lo, float hi) {
    return f2bf(lo) | (f2bf(hi) << 16);
}

// half-exchange: swaps lanes[0:31] of a with lanes[32:63] of b (one VALU instr)
__device__ __forceinline__ void hswap(uint32 &a, uint32 &b, int h) {
#if __has_builtin(__builtin_amdgcn_permlane32_swap)
    u2v rr = __builtin_amdgcn_permlane32_swap(a, b, false, false);
    a = rr.x; b = rr.y;
#else
    uint32 xa = (uint32)__shfl_xor((int)a, 32, 64);
    uint32 xb = (uint32)__shfl_xor((int)b, 32, 64);
    uint32 na = (h == 0) ? xb : a;
    uint32 nb = (h == 0) ? b  : xa;
    a = na; b = nb;
#endif
}

// ---------------------------------------------------------------------------
// PartialDense body (unchanged from R9): Y[:, c0:c0+32) per token-half.
// MODE: 0 = fp32 merged [t][a][c]; 1 = bf16 separated [bh][t][p*16+m];
//       2 = bf16 separated TRANSPOSED [bh][t][u'*16+m]  (for V)
// ---------------------------------------------------------------------------
template<int MODE>
__device__ __forceinline__ void pdense_body(
    const float* __restrict__ Xp,
    const float* __restrict__ Wr, const float* __restrict__ Wc,
    const float* __restrict__ bias, void* __restrict__ dstv,
    float scale, int token, int half)
{
    __shared__ float XsT[64 * 68];
    __shared__ float T1r[64 * 36];

    const int tid = threadIdx.x;     // 0..127
    const int g4 = tid >> 3;         // 0..15 (a/i quad)
    const int cq = tid & 7;          // 0..7  (c quad within half)
    const int c0 = half * 32 + cq * 4;

    #pragma unroll
    for (int rep = 0; rep < 32; ++rep) {
        int idx = tid + rep * 128;   // = i*64 + j
        int i = idx >> 6, j = idx & 63;
        XsT[j * 68 + i] = Xp[idx];
    }
    __syncthreads();

    {
        const float4* X4 = (const float4*)XsT;
        float4 a0 = {0,0,0,0}, a1 = {0,0,0,0}, a2 = {0,0,0,0}, a3 = {0,0,0,0};
        #pragma unroll 8
        for (int j = 0; j < 64; ++j) {
            float4 xv = X4[j * 17 + g4];
            float4 wv = *(const float4*)&Wc[j * 64 + c0];
            a0.x = fmaf(xv.x, wv.x, a0.x); a0.y = fmaf(xv.x, wv.y, a0.y);
            a0.z = fmaf(xv.x, wv.z, a0.z); a0.w = fmaf(xv.x, wv.w, a0.w);
            a1.x = fmaf(xv.y, wv.x, a1.x); a1.y = fmaf(xv.y, wv.y, a1.y);
            a1.z = fmaf(xv.y, wv.z, a1.z); a1.w = fmaf(xv.y, wv.w, a1.w);
            a2.x = fmaf(xv.z, wv.x, a2.x); a2.y = fmaf(xv.z, wv.y, a2.y);
            a2.z = fmaf(xv.z, wv.z, a2.z); a2.w = fmaf(xv.z, wv.w, a2.w);
            a3.x = fmaf(xv.w, wv.x, a3.x); a3.y = fmaf(xv.w, wv.y, a3.y);
            a3.z = fmaf(xv.w, wv.z, a3.z); a3.w = fmaf(xv.w, wv.w, a3.w);
        }
        *(float4*)&T1r[(g4 * 4 + 0) * 36 + cq * 4] = a0;
        *(float4*)&T1r[(g4 * 4 + 1) * 36 + cq * 4] = a1;
        *(float4*)&T1r[(g4 * 4 + 2) * 36 + cq * 4] = a2;
        *(float4*)&T1r[(g4 * 4 + 3) * 36 + cq * 4] = a3;
    }
    __syncthreads();

    float4 y0 = {0,0,0,0}, y1 = {0,0,0,0}, y2 = {0,0,0,0}, y3 = {0,0,0,0};
    #pragma unroll 8
    for (int i = 0; i < 64; ++i) {
        float4 wv = *(const float4*)&Wr[i * 64 + g4 * 4];
        float4 tv = *(const float4*)&T1r[i * 36 + cq * 4];
        y0.x = fmaf(wv.x, tv.x, y0.x); y0.y = fmaf(wv.x, tv.y, y0.y);
        y0.z = fmaf(wv.x, tv.z, y0.z); y0.w = fmaf(wv.x, tv.w, y0.w);
        y1.x = fmaf(wv.y, tv.x, y1.x); y1.y = fmaf(wv.y, tv.y, y1.y);
        y1.z = fmaf(wv.y, tv.z, y1.z); y1.w = fmaf(wv.y, tv.w, y1.w);
        y2.x = fmaf(wv.z, tv.x, y2.x); y2.y = fmaf(wv.z, tv.y, y2.y);
        y2.z = fmaf(wv.z, tv.z, y2.z); y2.w = fmaf(wv.z, tv.w, y2.w);
        y3.x = fmaf(wv.w, tv.x, y3.x); y3.y = fmaf(wv.w, tv.y, y3.y);
        y3.z = fmaf(wv.w, tv.z, y3.z); y3.w = fmaf(wv.w, tv.w, y3.w);
    }

    const int bI = token / TT, t = token % TT;
    float z[4][4];
    {
        float4 ys[4] = {y0, y1, y2, y3};
        #pragma unroll
        for (int aa = 0; aa < 4; ++aa) {
            float4 bv = *(const float4*)&bias[(g4 * 4 + aa) * 64 + c0];
            z[aa][0] = (ys[aa].x + bv.x) * scale;
            z[aa][1] = (ys[aa].y + bv.y) * scale;
            z[aa][2] = (ys[aa].z + bv.z) * scale;
            z[aa][3] = (ys[aa].w + bv.w) * scale;
        }
    }

    if (MODE == 0) {
        #pragma unroll
        for (int aa = 0; aa < 4; ++aa) {
            float4 v = {z[aa][0], z[aa][1], z[aa][2], z[aa][3]};
            *(float4*)((float*)dstv + (size_t)token * 4096 + (g4 * 4 + aa) * 64 + c0) = v;
        }
    } else if (MODE == 1) {
        const int r = c0 >> 4, cc = c0 & 15;
        #pragma unroll
        for (int aa = 0; aa < 4; ++aa) {
            int a = g4 * 4 + aa, lh = a >> 4, p = a & 15;
            U2 pk = { pkbf(z[aa][0], z[aa][1]), pkbf(z[aa][2], z[aa][3]) };
            *(U2*)((unsigned short*)dstv +
                   ((size_t)((bI * HEADS + lh * RH + r) * TT + t)) * 256 + p * 16 + cc) = pk;
        }
    } else {
        const int a0i = g4 * 4;
        const int lh = a0i >> 4, m0 = a0i & 15;
        #pragma unroll
        for (int cc2 = 0; cc2 < 4; ++cc2) {
            int cfull = c0 + cc2, r = cfull >> 4, up = cfull & 15;
            U2 pk = { pkbf(z[0][cc2], z[1][cc2]), pkbf(z[2][cc2], z[3][cc2]) };
            *(U2*)((unsigned short*)dstv +
                   ((size_t)((bI * HEADS + lh * RH + r) * TT + t)) * 256 + up * 16 + m0) = pk;
        }
    }
}

// Fused q/k/v projection (+ att zerofill tail blocks)
__global__ __launch_bounds__(128, 2) void pdense_qkv_kernel(
    const float* __restrict__ Xq, const float* __restrict__ Xk, const float* __restrict__ Xv,
    const float* __restrict__ Wq_row, const float* __restrict__ Wq_col, const float* __restrict__ bq,
    const float* __restrict__ Wk_row, const float* __restrict__ Wk_col, const float* __restrict__ bk,
    const float* __restrict__ Wv_row, const float* __restrict__ Wv_col, const float* __restrict__ bv,
    unsigned short* __restrict__ q_bf, unsigned short* __restrict__ k_bf,
    unsigned short* __restrict__ vt_bf, float* __restrict__ att)
{
    const int bid = blockIdx.x;
    if (bid >= 3 * NTOK * 2) {
        const int zb = bid - 3 * NTOK * 2;
        float4* a4 = (float4*)att;
        #pragma unroll
        for (int k = 0; k < 16; ++k)
            a4[(size_t)zb * 2048 + k * 128 + threadIdx.x] = float4{0.f, 0.f, 0.f, 0.f};
        return;
    }
    const int which = bid / (NTOK * 2);
    const int rem   = bid % (NTOK * 2);
    const int token = rem >> 1, half = rem & 1;

    if (which == 0)   // Q: fold pdense/h, logits/h AND log2(e) for exp2
        pdense_body<1>(Xq + (size_t)token * 4096, Wq_row, Wq_col, bq, q_bf,
                       INV_H * INV_H * LOG2E, token, half);
    else if (which == 1)
        pdense_body<1>(Xk + (size_t)token * 4096, Wk_row, Wk_col, bk, k_bf, INV_H, token, half);
    else
        pdense_body<2>(Xv + (size_t)token * 4096, Wv_row, Wv_col, bv, vt_bf, INV_H, token, half);
}

__global__ __launch_bounds__(128, 2) void pdense_out_kernel(
    const float* __restrict__ X, const float* __restrict__ Wr,
    const float* __restrict__ Wc, const float* __restrict__ bias,
    float* __restrict__ dst)
{
    const int token = blockIdx.x >> 1, half = blockIdx.x & 1;
    pdense_body<0>(X + (size_t)token * 4096, Wr, Wc, bias, dst, INV_H, token, half);
}

// ---------------------------------------------------------------------------
// MFMA attention v2: 32x32x16 (K=16 exact), 4-wave blocks with j-split.
// Block = (batch, valid head, 2 query tokens); wave w owns j in [24w, 24w+24).
// QK (swapped): D[row=(j_loc,u)][col=(i,p)] = one mfma per 2 j's.
// Z combined across waves in LDS; PV A-frag built from D via 2 permlane32_swap
// per j_loc (pure VALU, no LDS); PV partials combined in LDS.
// ---------------------------------------------------------------------------
__global__ __launch_bounds__(256, 4) void attn_kernel(
    const unsigned short* __restrict__ q_bf,
    const unsigned short* __restrict__ k_bf,
    const unsigned short* __restrict__ vt_bf,
    float* __restrict__ att)
{
    __shared__ float lds_z[4][64][9];    // padded: stride 9 (odd) = conflict-free
    __shared__ float lds_pv[4][64][17];  // padded: stride 17

    const int ip = blockIdx.x % (TT / 2);
    const int vh = (blockIdx.x / (TT / 2)) % VHEADS;
    const int bI = blockIdx.x / ((TT / 2) * VHEADS);
    const int l = (vh >= 1) + (vh >= 3) + (vh >= 6);
    const int r = vh - (l * (l + 1)) / 2;
    const int head = l * RH + r;
    const int i0 = ip * 2;
    const int lane = threadIdx.x & 63;
    const int wv = threadIdx.x >> 6;
    const int c5 = lane & 31;
    const int h  = lane >> 5;

    const size_t hb = (size_t)(bI * HEADS + head) * TT * 256;
    const int frow = (c5 & 15) * 16 + 8 * h;   // element offset within a 16x16 tile

    // Q B-frag: col = (i_loc, p) = c5, k = m = 8h+s
    s8v qf = *(const s8v*)(q_bf + hb + (size_t)(i0 + (c5 >> 4)) * 256 + frow);
    const unsigned short* kb = k_bf + hb + frow;   // + j*256 ; A row = (j_loc, u)
    const unsigned short* vb = vt_bf + hb + frow;  // + j*256 ; B col = u', k = m

    const int jb = wv * (TT / 4);   // 24 j's per wave
    const f16v fz16 = {0,0,0,0,0,0,0,0,0,0,0,0,0,0,0,0};

    // ---- pass 1: softmax denominators Z[(i,p), u] (reg-compact: ls[t] = u-slot t) ----
    float ls[8] = {0,0,0,0,0,0,0,0};
    #pragma unroll 3
    for (int jp = 0; jp < 12; ++jp) {
        const int j0g = jb + jp * 2;
        s8v kf = *(const s8v*)(kb + (size_t)(j0g + (c5 >> 4)) * 256);
        f16v d = __builtin_amdgcn_mfma_f32_32x32x16_bf16(kf, qf, fz16, 0, 0, 0);
        #pragma unroll
        for (int t = 0; t < 8; ++t)
            ls[t] += exp2f(d[t]) + exp2f(d[t + 8]);   // j_loc 0 and 1 share u-slot
    }
    #pragma unroll
    for (int t = 0; t < 8; ++t) lds_z[wv][lane][t] = ls[t];
    __syncthreads();
    float inv[8];
    #pragma unroll
    for (int t = 0; t < 8; ++t) {
        float s = lds_z[0][lane][t] + lds_z[1][lane][t]
                + lds_z[2][lane][t] + lds_z[3][lane][t];
        inv[t] = 1.f / s;
    }

    // ---- pass 2: recompute, normalize, redistribute (permlane), PV ----
    f16v pv = fz16;
    #pragma unroll 2
    for (int jp = 0; jp < 12; ++jp) {
        const int j0g = jb + jp * 2;
        s8v kf = *(const s8v*)(kb + (size_t)(j0g + (c5 >> 4)) * 256);
        f16v d = __builtin_amdgcn_mfma_f32_32x32x16_bf16(kf, qf, fz16, 0, 0, 0);
        float w[16];
        #pragma unroll
        for (int t = 0; t < 8; ++t) {
            w[t]     = exp2f(d[t])     * inv[t];
            w[t + 8] = exp2f(d[t + 8]) * inv[t];
        }
        // pack (compiler fuses pairs to v_cvt_pk_bf16_f32)
        uint32 A0 = pkbf(w[0],  w[1]),  A1 = pkbf(w[2],  w[3]);
        uint32 A2 = pkbf(w[4],  w[5]),  A3 = pkbf(w[6],  w[7]);
        uint32 B0 = pkbf(w[8],  w[9]),  B1 = pkbf(w[10], w[11]);
        uint32 B2 = pkbf(w[12], w[13]), B3 = pkbf(w[14], w[15]);
        // half-exchange: after hswap(X2, X0): reg0 = X0, reg2 = X2 hold the
        // PV A-frag words (m=8h+0..1 and 8h+4..5) for this lane's half.
        hswap(A2, A0, h); hswap(A3, A1, h);
        hswap(B2, B0, h); hswap(B3, B1, h);
        U4 fa = {A0, A1, A2, A3};
        U4 fb = {B0, B1, B2, B3};
        s8v vf0 = *(const s8v*)(vb + (size_t)(j0g + 0) * 256);
        s8v vf1 = *(const s8v*)(vb + (size_t)(j0g + 1) * 256);
        pv = __builtin_amdgcn_mfma_f32_32x32x16_bf16(__builtin_bit_cast(s8v, fa), vf0, pv, 0, 0, 0);
        pv = __builtin_amdgcn_mfma_f32_32x32x16_bf16(__builtin_bit_cast(s8v, fb), vf1, pv, 0, 0, 0);
    }

    #pragma unroll
    for (int t = 0; t < 16; ++t) lds_pv[wv][lane][t] = pv[t];
    __syncthreads();

    // combine partial PV across waves; wave wv stores D-regs [4wv, 4wv+4)
    if (c5 < 16) {   // cols 16-31 are duplicates (V cols replicated)
        #pragma unroll
        for (int rr = 0; rr < 4; ++rr) {
            const int reg = wv * 4 + rr;
            float v = lds_pv[0][lane][reg] + lds_pv[1][lane][reg]
                    + lds_pv[2][lane][reg] + lds_pv[3][lane][reg];
            const int row = rr + 8 * wv + 4 * h;   // = (reg&3)+8*(reg>>2)+4*h
            const int i = row >> 4, p = row & 15;
            att[((size_t)(bI * TT + i0 + i) * DD + l * 16 + p) * DD + r * 16 + c5] = v;
        }
    }
}

// ---------------------------------------------------------------------------
extern "C" void kernel_launch(void* const* d_in, const int* in_sizes, int n_in,
                              void* d_out, int out_size, void* d_ws, size_t ws_size,
                              hipStream_t stream) {
    const float* queries = (const float*)d_in[0];
    const float* keys    = (const float*)d_in[1];
    const float* values  = (const float*)d_in[2];
    const float* Wq_row  = (const float*)d_in[3];
    const float* Wq_col  = (const float*)d_in[4];
    const float* bq      = (const float*)d_in[5];
    const float* Wk_row  = (const float*)d_in[6];
    const float* Wk_col  = (const float*)d_in[7];
    const float* bk      = (const float*)d_in[8];
    const float* Wv_row  = (const float*)d_in[9];
    const float* Wv_col  = (const float*)d_in[10];
    const float* bv      = (const float*)d_in[11];
    const float* Wo_row  = (const float*)d_in[12];
    const float* Wo_col  = (const float*)d_in[13];
    const float* bo      = (const float*)d_in[14];
    float* out = (float*)d_out;

    const size_t SEP = (size_t)BB * HEADS * TT * 256;   // 786432 elements
    unsigned short* q_bf  = (unsigned short*)d_ws;
    unsigned short* k_bf  = q_bf + SEP;
    unsigned short* vt_bf = k_bf + SEP;
    float* att = (float*)(vt_bf + SEP);                 // 16B-aligned

    pdense_qkv_kernel<<<3 * NTOK * 2 + ZBLK, 128, 0, stream>>>(
        queries, keys, values,
        Wq_row, Wq_col, bq, Wk_row, Wk_col, bk, Wv_row, Wv_col, bv,
        q_bf, k_bf, vt_bf, att);

    attn_kernel<<<BB * VHEADS * (TT / 2), 256, 0, stream>>>(q_bf, k_bf, vt_bf, att);

    pdense_out_kernel<<<NTOK * 2, 128, 0, stream>>>(att, Wo_row, Wo_col, bo, out);
}

// Round 13
// 65.093 us; speedup vs baseline: 1.3804x; 1.0218x over previous
//
#include <hip/hip_runtime.h>
#include <hip/hip_bf16.h>
#include <math.h>

typedef unsigned int uint32;
typedef unsigned short ushort_t;
typedef __attribute__((ext_vector_type(8))) short s8v;
typedef __attribute__((ext_vector_type(16))) float f16v;
typedef __attribute__((ext_vector_type(2))) unsigned int u2v;

// Problem constants
#define LH 4
#define RH 4
#define DD 64
#define BB 2
#define TT 96
#define NTOK (BB*TT)           // 192
#define HEADS 16
#define VHEADS 10              // heads with r <= l
#define INV_H 0.0625f
#define LOG2E 1.4426950408889634f
#define QKV_BLOCKS 288         // 1152 waves / 4
#define ZF_BLOCKS 48           // att zerofill tail blocks

struct U2 { uint32 x, y; };
struct U4 { uint32 x, y, z, w; };

__device__ __forceinline__ uint32 f2bf(float f) {
    return (uint32)__builtin_bit_cast(ushort_t, __float2bfloat16(f));
}
__device__ __forceinline__ uint32 pkbf(float lo, float hi) {
    return f2bf(lo) | (f2bf(hi) << 16);
}
__device__ __forceinline__ float bf2f(uint32 u) {
    return __uint_as_float(u << 16);
}
// exchange lanes[0:31] of a with lanes[32:63] of b (verified in R10 attn)
__device__ __forceinline__ void hswap(uint32 &a, uint32 &b, int h) {
#if __has_builtin(__builtin_amdgcn_permlane32_swap)
    u2v rr = __builtin_amdgcn_permlane32_swap(a, b, false, false);
    a = rr.x; b = rr.y;
#else
    uint32 xa = (uint32)__shfl_xor((int)a, 32, 64);
    uint32 xb = (uint32)__shfl_xor((int)b, 32, 64);
    uint32 na = (h == 0) ? xb : a;
    uint32 nb = (h == 0) ? b  : xa;
    a = na; b = nb;
#endif
}

// ---------------------------------------------------------------------------
// Weight prep (verbatim R12): transposed bf16 weights + transposed biases.
// ---------------------------------------------------------------------------
__global__ __launch_bounds__(256) void wprep_kernel(
    const float* __restrict__ Wq_row, const float* __restrict__ Wq_col, const float* __restrict__ bq,
    const float* __restrict__ Wk_row, const float* __restrict__ Wk_col, const float* __restrict__ bk,
    const float* __restrict__ Wv_row, const float* __restrict__ Wv_col, const float* __restrict__ bv,
    const float* __restrict__ Wo_row, const float* __restrict__ Wo_col, const float* __restrict__ bo,
    ushort_t* __restrict__ wct, ushort_t* __restrict__ wrt, float* __restrict__ bT)
{
    const int task = blockIdx.x;
    const int tid = threadIdx.x;
    #pragma unroll
    for (int e = 0; e < 16; ++e) {
        const int idx = e * 256 + tid;
        const int src = (idx & 63) * 64 + (idx >> 6);
        switch (task) {
        case 0: wct[idx]          = (ushort_t)f2bf(Wq_col[src]); break;
        case 1: wct[4096 + idx]   = (ushort_t)f2bf(Wk_col[src]); break;
        case 2: wct[8192 + idx]   = (ushort_t)f2bf(Wv_col[src]); break;
        case 3: wrt[idx]          = (ushort_t)f2bf(Wq_row[src]); break;
        case 4: wrt[4096 + idx]   = (ushort_t)f2bf(Wk_row[src]); break;
        case 5: wrt[8192 + idx]   = (ushort_t)f2bf(Wv_row[src]); break;
        case 6: bT[idx]           = bq[src]; break;
        case 7: bT[4096 + idx]    = bk[src]; break;
        default: bT[8192 + idx]   = bv[src]; break;
        }
    }
}

// ---------------------------------------------------------------------------
// MFMA q/k/v projections — R13 bisection: the ONLY change vs R12 is that the
// GEMM2 B-fragments are rebuilt via an LDS transpose roundtrip instead of the
// in-register hswap path. (Store T1 D-regs to per-wave LDS [c][i] using the
// HW-verified D-row formula; read back contiguous — the exact memory-load
// pattern the attn kernel verified for B-operands.)
// ---------------------------------------------------------------------------
__global__ __launch_bounds__(256) void pdense_qkv_mfma(
    const float* __restrict__ Xq, const float* __restrict__ Xk, const float* __restrict__ Xv,
    const ushort_t* __restrict__ wct, const ushort_t* __restrict__ wrt,
    const float* __restrict__ bT,
    ushort_t* __restrict__ q_bf, ushort_t* __restrict__ k_bf,
    ushort_t* __restrict__ vt_bf, float* __restrict__ att)
{
    __shared__ float lds_t1[4][32][68];   // per-wave slab: [c5][i], pad 68

    const int bid = blockIdx.x;
    if (bid >= QKV_BLOCKS) {
        const int zb = bid - QKV_BLOCKS;
        float4* a4 = (float4*)att;
        #pragma unroll
        for (int it = 0; it < 16; ++it)
            a4[(size_t)zb * 4096 + it * 256 + threadIdx.x] = float4{0.f, 0.f, 0.f, 0.f};
        return;
    }
    const int wv = threadIdx.x >> 6;
    const int task = bid * 4 + wv;                   // 0..1151
    const int proj = task / (NTOK * 2);
    const int rem  = task % (NTOK * 2);
    const int token = rem >> 1;
    const int ch = rem & 1;
    const int lane = threadIdx.x & 63;
    const int c5 = lane & 31, h = lane >> 5;
    const int c = ch * 32 + c5;
    const int bI = token / TT, t = token % TT;

    const float* X = (proj == 0) ? Xq : (proj == 1) ? Xk : Xv;
    const float* Xp = X + (size_t)token * 4096;
    const ushort_t* wc = wct + proj * 4096;
    const ushort_t* wr = wrt + proj * 4096;
    const float*    bt = bT + proj * 4096;
    const float scale = (proj == 0) ? (INV_H * INV_H * LOG2E) : INV_H;

    const f16v fz = {0,0,0,0,0,0,0,0,0,0,0,0,0,0,0,0};

    // GEMM1: T1 = X @ Wc ; lane (c5,h) reg t -> T1[i=(t&3)+8*(t>>2)+4h (+32)][c]
    f16v t1_0 = fz, t1_1 = fz;
    #pragma unroll
    for (int n = 0; n < 4; ++n) {
        s8v bf = *(const s8v*)(wc + c * 64 + n * 16 + 8 * h);
        {
            const float* xr = Xp + (size_t)c5 * 64 + n * 16 + 8 * h;
            float4 xa = *(const float4*)xr, xb = *(const float4*)(xr + 4);
            U4 u = { pkbf(xa.x, xa.y), pkbf(xa.z, xa.w), pkbf(xb.x, xb.y), pkbf(xb.z, xb.w) };
            t1_0 = __builtin_amdgcn_mfma_f32_32x32x16_bf16(__builtin_bit_cast(s8v, u), bf, t1_0, 0, 0, 0);
        }
        {
            const float* xr = Xp + (size_t)(32 + c5) * 64 + n * 16 + 8 * h;
            float4 xa = *(const float4*)xr, xb = *(const float4*)(xr + 4);
            U4 u = { pkbf(xa.x, xa.y), pkbf(xa.z, xa.w), pkbf(xb.x, xb.y), pkbf(xb.z, xb.w) };
            t1_1 = __builtin_amdgcn_mfma_f32_32x32x16_bf16(__builtin_bit_cast(s8v, u), bf, t1_1, 0, 0, 0);
        }
    }

    // ---- LDS transpose roundtrip (replaces hswap rebuild) ----
    #pragma unroll
    for (int tt = 0; tt < 16; ++tt) {
        const int i = (tt & 3) + 8 * (tt >> 2) + 4 * h;
        lds_t1[wv][c5][i]      = t1_0[tt];
        lds_t1[wv][c5][32 + i] = t1_1[tt];
    }
    __syncthreads();

    s8v bfr[4];
    #pragma unroll
    for (int n = 0; n < 4; ++n) {
        const float* p = &lds_t1[wv][c5][n * 16 + 8 * h];
        float4 xa = *(const float4*)p, xb = *(const float4*)(p + 4);
        U4 u = { pkbf(xa.x, xa.y), pkbf(xa.z, xa.w), pkbf(xb.x, xb.y), pkbf(xb.z, xb.w) };
        bfr[n] = __builtin_bit_cast(s8v, u);
    }

    // GEMM2 + epilogue
    #pragma unroll
    for (int At = 0; At < 2; ++At) {
        f16v y = fz;
        #pragma unroll
        for (int n = 0; n < 4; ++n) {
            s8v af = *(const s8v*)(wr + (size_t)(32 * At + c5) * 64 + n * 16 + 8 * h);
            y = __builtin_amdgcn_mfma_f32_32x32x16_bf16(af, bfr[n], y, 0, 0, 0);
        }
        #pragma unroll
        for (int rg = 0; rg < 4; ++rg) {
            float4 bv = *(const float4*)(bt + c * 64 + 32 * At + 8 * rg + 4 * h);
            float be[4] = {bv.x, bv.y, bv.z, bv.w};
            #pragma unroll
            for (int e = 0; e < 4; ++e) {
                const int a = 32 * At + 8 * rg + 4 * h + e;
                const float val = (y[rg * 4 + e] + be[e]) * scale;
                const ushort_t ov = (ushort_t)f2bf(val);
                const size_t base =
                    ((size_t)((bI * HEADS + (a >> 4) * RH + (c >> 4)) * TT + t)) * 256;
                if (proj == 0)      q_bf[base + (a & 15) * 16 + (c & 15)] = ov;
                else if (proj == 1) k_bf[base + (a & 15) * 16 + (c & 15)] = ov;
                else                vt_bf[base + (c & 15) * 16 + (a & 15)] = ov;
            }
        }
    }
}

// ---------------------------------------------------------------------------
// R10's PROVEN fp32 VALU PartialDense (merged output) — out-projection.
// ---------------------------------------------------------------------------
__global__ __launch_bounds__(128, 2) void pdense_out_fp32(
    const float* __restrict__ Xall, const float* __restrict__ Wr,
    const float* __restrict__ Wc, const float* __restrict__ bias,
    float* __restrict__ dst)
{
    __shared__ float XsT[64 * 68];
    __shared__ float T1r[64 * 36];

    const int token = blockIdx.x >> 1, half = blockIdx.x & 1;
    const float* Xp = Xall + (size_t)token * 4096;

    const int tid = threadIdx.x;     // 0..127
    const int g4 = tid >> 3;         // 0..15
    const int cq = tid & 7;          // 0..7
    const int c0 = half * 32 + cq * 4;

    #pragma unroll
    for (int rep = 0; rep < 32; ++rep) {
        int idx = tid + rep * 128;
        int i = idx >> 6, j = idx & 63;
        XsT[j * 68 + i] = Xp[idx];
    }
    __syncthreads();

    {
        const float4* X4 = (const float4*)XsT;
        float4 a0 = {0,0,0,0}, a1 = {0,0,0,0}, a2 = {0,0,0,0}, a3 = {0,0,0,0};
        #pragma unroll 8
        for (int j = 0; j < 64; ++j) {
            float4 xv = X4[j * 17 + g4];
            float4 wv = *(const float4*)&Wc[j * 64 + c0];
            a0.x = fmaf(xv.x, wv.x, a0.x); a0.y = fmaf(xv.x, wv.y, a0.y);
            a0.z = fmaf(xv.x, wv.z, a0.z); a0.w = fmaf(xv.x, wv.w, a0.w);
            a1.x = fmaf(xv.y, wv.x, a1.x); a1.y = fmaf(xv.y, wv.y, a1.y);
            a1.z = fmaf(xv.y, wv.z, a1.z); a1.w = fmaf(xv.y, wv.w, a1.w);
            a2.x = fmaf(xv.z, wv.x, a2.x); a2.y = fmaf(xv.z, wv.y, a2.y);
            a2.z = fmaf(xv.z, wv.z, a2.z); a2.w = fmaf(xv.z, wv.w, a2.w);
            a3.x = fmaf(xv.w, wv.x, a3.x); a3.y = fmaf(xv.w, wv.y, a3.y);
            a3.z = fmaf(xv.w, wv.z, a3.z); a3.w = fmaf(xv.w, wv.w, a3.w);
        }
        *(float4*)&T1r[(g4 * 4 + 0) * 36 + cq * 4] = a0;
        *(float4*)&T1r[(g4 * 4 + 1) * 36 + cq * 4] = a1;
        *(float4*)&T1r[(g4 * 4 + 2) * 36 + cq * 4] = a2;
        *(float4*)&T1r[(g4 * 4 + 3) * 36 + cq * 4] = a3;
    }
    __syncthreads();

    float4 y0 = {0,0,0,0}, y1 = {0,0,0,0}, y2 = {0,0,0,0}, y3 = {0,0,0,0};
    #pragma unroll 8
    for (int i = 0; i < 64; ++i) {
        float4 wv = *(const float4*)&Wr[i * 64 + g4 * 4];
        float4 tv = *(const float4*)&T1r[i * 36 + cq * 4];
        y0.x = fmaf(wv.x, tv.x, y0.x); y0.y = fmaf(wv.x, tv.y, y0.y);
        y0.z = fmaf(wv.x, tv.z, y0.z); y0.w = fmaf(wv.x, tv.w, y0.w);
        y1.x = fmaf(wv.y, tv.x, y1.x); y1.y = fmaf(wv.y, tv.y, y1.y);
        y1.z = fmaf(wv.y, tv.z, y1.z); y1.w = fmaf(wv.y, tv.w, y1.w);
        y2.x = fmaf(wv.z, tv.x, y2.x); y2.y = fmaf(wv.z, tv.y, y2.y);
        y2.z = fmaf(wv.z, tv.z, y2.z); y2.w = fmaf(wv.z, tv.w, y2.w);
        y3.x = fmaf(wv.w, tv.x, y3.x); y3.y = fmaf(wv.w, tv.y, y3.y);
        y3.z = fmaf(wv.w, tv.z, y3.z); y3.w = fmaf(wv.w, tv.w, y3.w);
    }

    float4 ys[4] = {y0, y1, y2, y3};
    #pragma unroll
    for (int aa = 0; aa < 4; ++aa) {
        int a = g4 * 4 + aa;
        float4 bv = *(const float4*)&bias[a * 64 + c0];
        float4 v;
        v.x = (ys[aa].x + bv.x) * INV_H; v.y = (ys[aa].y + bv.y) * INV_H;
        v.z = (ys[aa].z + bv.z) * INV_H; v.w = (ys[aa].w + bv.w) * INV_H;
        *(float4*)(dst + (size_t)token * 4096 + a * 64 + c0) = v;
    }
}

// ---------------------------------------------------------------------------
// MFMA attention v2 (verbatim from R10, verified).
// ---------------------------------------------------------------------------
__global__ __launch_bounds__(256, 4) void attn_kernel(
    const ushort_t* __restrict__ q_bf,
    const ushort_t* __restrict__ k_bf,
    const ushort_t* __restrict__ vt_bf,
    float* __restrict__ att)
{
    __shared__ float lds_z[4][64][9];
    __shared__ float lds_pv[4][64][17];

    const int ip = blockIdx.x % (TT / 2);
    const int vh = (blockIdx.x / (TT / 2)) % VHEADS;
    const int bI = blockIdx.x / ((TT / 2) * VHEADS);
    const int l = (vh >= 1) + (vh >= 3) + (vh >= 6);
    const int r = vh - (l * (l + 1)) / 2;
    const int head = l * RH + r;
    const int i0 = ip * 2;
    const int lane = threadIdx.x & 63;
    const int wv = threadIdx.x >> 6;
    const int c5 = lane & 31;
    const int h  = lane >> 5;

    const size_t hb = (size_t)(bI * HEADS + head) * TT * 256;
    const int frow = (c5 & 15) * 16 + 8 * h;

    s8v qf = *(const s8v*)(q_bf + hb + (size_t)(i0 + (c5 >> 4)) * 256 + frow);
    const ushort_t* kb = k_bf + hb + frow;
    const ushort_t* vb = vt_bf + hb + frow;

    const int jb = wv * (TT / 4);
    const f16v fz16 = {0,0,0,0,0,0,0,0,0,0,0,0,0,0,0,0};

    float ls[8] = {0,0,0,0,0,0,0,0};
    #pragma unroll 3
    for (int jp = 0; jp < 12; ++jp) {
        const int j0g = jb + jp * 2;
        s8v kf = *(const s8v*)(kb + (size_t)(j0g + (c5 >> 4)) * 256);
        f16v d = __builtin_amdgcn_mfma_f32_32x32x16_bf16(kf, qf, fz16, 0, 0, 0);
        #pragma unroll
        for (int t = 0; t < 8; ++t)
            ls[t] += exp2f(d[t]) + exp2f(d[t + 8]);
    }
    #pragma unroll
    for (int t = 0; t < 8; ++t) lds_z[wv][lane][t] = ls[t];
    __syncthreads();
    float inv[8];
    #pragma unroll
    for (int t = 0; t < 8; ++t) {
        float s = lds_z[0][lane][t] + lds_z[1][lane][t]
                + lds_z[2][lane][t] + lds_z[3][lane][t];
        inv[t] = 1.f / s;
    }

    f16v pv = fz16;
    #pragma unroll 2
    for (int jp = 0; jp < 12; ++jp) {
        const int j0g = jb + jp * 2;
        s8v kf = *(const s8v*)(kb + (size_t)(j0g + (c5 >> 4)) * 256);
        f16v d = __builtin_amdgcn_mfma_f32_32x32x16_bf16(kf, qf, fz16, 0, 0, 0);
        float w[16];
        #pragma unroll
        for (int t = 0; t < 8; ++t) {
            w[t]     = exp2f(d[t])     * inv[t];
            w[t + 8] = exp2f(d[t + 8]) * inv[t];
        }
        uint32 A0 = pkbf(w[0],  w[1]),  A1 = pkbf(w[2],  w[3]);
        uint32 A2 = pkbf(w[4],  w[5]),  A3 = pkbf(w[6],  w[7]);
        uint32 B0 = pkbf(w[8],  w[9]),  B1 = pkbf(w[10], w[11]);
        uint32 B2 = pkbf(w[12], w[13]), B3 = pkbf(w[14], w[15]);
        hswap(A2, A0, h); hswap(A3, A1, h);
        hswap(B2, B0, h); hswap(B3, B1, h);
        U4 fa = {A0, A1, A2, A3};
        U4 fb = {B0, B1, B2, B3};
        s8v vf0 = *(const s8v*)(vb + (size_t)(j0g + 0) * 256);
        s8v vf1 = *(const s8v*)(vb + (size_t)(j0g + 1) * 256);
        pv = __builtin_amdgcn_mfma_f32_32x32x16_bf16(__builtin_bit_cast(s8v, fa), vf0, pv, 0, 0, 0);
        pv = __builtin_amdgcn_mfma_f32_32x32x16_bf16(__builtin_bit_cast(s8v, fb), vf1, pv, 0, 0, 0);
    }

    #pragma unroll
    for (int t = 0; t < 16; ++t) lds_pv[wv][lane][t] = pv[t];
    __syncthreads();

    if (c5 < 16) {
        #pragma unroll
        for (int rr = 0; rr < 4; ++rr) {
            const int reg = wv * 4 + rr;
            float v = lds_pv[0][lane][reg] + lds_pv[1][lane][reg]
                    + lds_pv[2][lane][reg] + lds_pv[3][lane][reg];
            const int row = rr + 8 * wv + 4 * h;
            const int i = row >> 4, p = row & 15;
            att[((size_t)(bI * TT + i0 + i) * DD + l * 16 + p) * DD + r * 16 + c5] = v;
        }
    }
}

// ---------------------------------------------------------------------------
extern "C" void kernel_launch(void* const* d_in, const int* in_sizes, int n_in,
                              void* d_out, int out_size, void* d_ws, size_t ws_size,
                              hipStream_t stream) {
    const float* queries = (const float*)d_in[0];
    const float* keys    = (const float*)d_in[1];
    const float* values  = (const float*)d_in[2];
    const float* Wq_row  = (const float*)d_in[3];
    const float* Wq_col  = (const float*)d_in[4];
    const float* bq      = (const float*)d_in[5];
    const float* Wk_row  = (const float*)d_in[6];
    const float* Wk_col  = (const float*)d_in[7];
    const float* bk      = (const float*)d_in[8];
    const float* Wv_row  = (const float*)d_in[9];
    const float* Wv_col  = (const float*)d_in[10];
    const float* bv      = (const float*)d_in[11];
    const float* Wo_row  = (const float*)d_in[12];
    const float* Wo_col  = (const float*)d_in[13];
    const float* bo      = (const float*)d_in[14];
    float* out = (float*)d_out;

    const size_t SEP = (size_t)BB * HEADS * TT * 256;   // 786432 elements
    ushort_t* q_bf  = (ushort_t*)d_ws;
    ushort_t* k_bf  = q_bf + SEP;
    ushort_t* vt_bf = k_bf + SEP;
    float*    att   = (float*)(vt_bf + SEP);
    ushort_t* wct   = (ushort_t*)(att + SEP);
    ushort_t* wrt   = wct + 3 * 4096;
    float*    bT    = (float*)(wrt + 3 * 4096);

    wprep_kernel<<<9, 256, 0, stream>>>(
        Wq_row, Wq_col, bq, Wk_row, Wk_col, bk, Wv_row, Wv_col, bv,
        Wo_row, Wo_col, bo, wct, wrt, bT);

    pdense_qkv_mfma<<<QKV_BLOCKS + ZF_BLOCKS, 256, 0, stream>>>(
        queries, keys, values, wct, wrt, bT, q_bf, k_bf, vt_bf, att);

    attn_kernel<<<BB * VHEADS * (TT / 2), 256, 0, stream>>>(q_bf, k_bf, vt_bf, att);

    pdense_out_fp32<<<NTOK * 2, 128, 0, stream>>>(att, Wo_row, Wo_col, bo, out);
}

// Round 14
// 62.513 us; speedup vs baseline: 1.4373x; 1.0413x over previous
//
#include <hip/hip_runtime.h>
#include <hip/hip_bf16.h>
#include <math.h>

typedef unsigned int uint32;
typedef unsigned short ushort_t;
typedef __attribute__((ext_vector_type(8))) short s8v;
typedef __attribute__((ext_vector_type(16))) float f16v;
typedef __attribute__((ext_vector_type(2))) unsigned int u2v;

// Problem constants
#define LH 4
#define RH 4
#define DD 64
#define BB 2
#define TT 96
#define NTOK (BB*TT)           // 192
#define HEADS 16
#define VHEADS 10              // heads with r <= l
#define INV_H 0.0625f
#define LOG2E 1.4426950408889634f
#define QKV_BLOCKS 288         // 1152 waves / 4
#define ZF_BLOCKS 48           // att zerofill tail blocks

struct U2 { uint32 x, y; };
struct U4 { uint32 x, y, z, w; };

__device__ __forceinline__ uint32 f2bf(float f) {
    return (uint32)__builtin_bit_cast(ushort_t, __float2bfloat16(f));
}
__device__ __forceinline__ uint32 pkbf(float lo, float hi) {
    return f2bf(lo) | (f2bf(hi) << 16);
}
__device__ __forceinline__ float bf2f(uint32 u) {
    return __uint_as_float(u << 16);
}
// hi/lo split of a pair into packed bf16 words (3-product split-GEMM)
__device__ __forceinline__ void hl_pair(float v0, float v1, uint32 &hw, uint32 &lw) {
    uint32 h0 = f2bf(v0), h1 = f2bf(v1);
    hw = h0 | (h1 << 16);
    lw = pkbf(v0 - bf2f(h0), v1 - bf2f(h1));
}
// exchange lanes[0:31] of a with lanes[32:63] of b — verified for A-frags (R10)
__device__ __forceinline__ void hswap(uint32 &a, uint32 &b, int h) {
#if __has_builtin(__builtin_amdgcn_permlane32_swap)
    u2v rr = __builtin_amdgcn_permlane32_swap(a, b, false, false);
    a = rr.x; b = rr.y;
#else
    uint32 xa = (uint32)__shfl_xor((int)a, 32, 64);
    uint32 xb = (uint32)__shfl_xor((int)b, 32, 64);
    uint32 na = (h == 0) ? xb : a;
    uint32 nb = (h == 0) ? b  : xa;
    a = na; b = nb;
#endif
}

// ---------------------------------------------------------------------------
// Weight prep: transposed bf16 weights (qkv), hi/lo transposed (out), biases.
// dst[idx], idx = c*64 + i  <-  src[i*64 + c]
// ---------------------------------------------------------------------------
__global__ __launch_bounds__(256) void wprep_kernel(
    const float* __restrict__ Wq_row, const float* __restrict__ Wq_col, const float* __restrict__ bq,
    const float* __restrict__ Wk_row, const float* __restrict__ Wk_col, const float* __restrict__ bk,
    const float* __restrict__ Wv_row, const float* __restrict__ Wv_col, const float* __restrict__ bv,
    const float* __restrict__ Wo_row, const float* __restrict__ Wo_col, const float* __restrict__ bo,
    ushort_t* __restrict__ wct, ushort_t* __restrict__ wrt, float* __restrict__ bT,
    ushort_t* __restrict__ woct_h, ushort_t* __restrict__ woct_l,
    ushort_t* __restrict__ wort_h, ushort_t* __restrict__ wort_l,
    float* __restrict__ boT)
{
    const int task = blockIdx.x;
    const int tid = threadIdx.x;
    #pragma unroll
    for (int e = 0; e < 16; ++e) {
        const int idx = e * 256 + tid;
        const int src = (idx & 63) * 64 + (idx >> 6);
        switch (task) {
        case 0: wct[idx]          = (ushort_t)f2bf(Wq_col[src]); break;
        case 1: wct[4096 + idx]   = (ushort_t)f2bf(Wk_col[src]); break;
        case 2: wct[8192 + idx]   = (ushort_t)f2bf(Wv_col[src]); break;
        case 3: wrt[idx]          = (ushort_t)f2bf(Wq_row[src]); break;
        case 4: wrt[4096 + idx]   = (ushort_t)f2bf(Wk_row[src]); break;
        case 5: wrt[8192 + idx]   = (ushort_t)f2bf(Wv_row[src]); break;
        case 6: bT[idx]           = bq[src]; break;
        case 7: bT[4096 + idx]    = bk[src]; break;
        case 8: bT[8192 + idx]    = bv[src]; break;
        case 9: {
            float v = Wo_col[src];
            uint32 hh = f2bf(v);
            woct_h[idx] = (ushort_t)hh;
            woct_l[idx] = (ushort_t)f2bf(v - bf2f(hh));
            break; }
        case 10: {
            float v = Wo_row[src];
            uint32 hh = f2bf(v);
            wort_h[idx] = (ushort_t)hh;
            wort_l[idx] = (ushort_t)f2bf(v - bf2f(hh));
            break; }
        default: boT[idx] = bo[src]; break;
        }
    }
}

// ---------------------------------------------------------------------------
// MFMA q/k/v projections (verbatim R13 — PROVEN).
// ---------------------------------------------------------------------------
__global__ __launch_bounds__(256) void pdense_qkv_mfma(
    const float* __restrict__ Xq, const float* __restrict__ Xk, const float* __restrict__ Xv,
    const ushort_t* __restrict__ wct, const ushort_t* __restrict__ wrt,
    const float* __restrict__ bT,
    ushort_t* __restrict__ q_bf, ushort_t* __restrict__ k_bf,
    ushort_t* __restrict__ vt_bf, float* __restrict__ att)
{
    __shared__ float lds_t1[4][32][68];   // per-wave slab: [c5][i], pad 68

    const int bid = blockIdx.x;
    if (bid >= QKV_BLOCKS) {
        const int zb = bid - QKV_BLOCKS;
        float4* a4 = (float4*)att;
        #pragma unroll
        for (int it = 0; it < 16; ++it)
            a4[(size_t)zb * 4096 + it * 256 + threadIdx.x] = float4{0.f, 0.f, 0.f, 0.f};
        return;
    }
    const int wv = threadIdx.x >> 6;
    const int task = bid * 4 + wv;                   // 0..1151
    const int proj = task / (NTOK * 2);
    const int rem  = task % (NTOK * 2);
    const int token = rem >> 1;
    const int ch = rem & 1;
    const int lane = threadIdx.x & 63;
    const int c5 = lane & 31, h = lane >> 5;
    const int c = ch * 32 + c5;
    const int bI = token / TT, t = token % TT;

    const float* X = (proj == 0) ? Xq : (proj == 1) ? Xk : Xv;
    const float* Xp = X + (size_t)token * 4096;
    const ushort_t* wc = wct + proj * 4096;
    const ushort_t* wr = wrt + proj * 4096;
    const float*    bt = bT + proj * 4096;
    const float scale = (proj == 0) ? (INV_H * INV_H * LOG2E) : INV_H;

    const f16v fz = {0,0,0,0,0,0,0,0,0,0,0,0,0,0,0,0};

    // GEMM1: T1 = X @ Wc ; lane (c5,h) reg t -> T1[i=(t&3)+8*(t>>2)+4h (+32)][c]
    f16v t1_0 = fz, t1_1 = fz;
    #pragma unroll
    for (int n = 0; n < 4; ++n) {
        s8v bf = *(const s8v*)(wc + c * 64 + n * 16 + 8 * h);
        {
            const float* xr = Xp + (size_t)c5 * 64 + n * 16 + 8 * h;
            float4 xa = *(const float4*)xr, xb = *(const float4*)(xr + 4);
            U4 u = { pkbf(xa.x, xa.y), pkbf(xa.z, xa.w), pkbf(xb.x, xb.y), pkbf(xb.z, xb.w) };
            t1_0 = __builtin_amdgcn_mfma_f32_32x32x16_bf16(__builtin_bit_cast(s8v, u), bf, t1_0, 0, 0, 0);
        }
        {
            const float* xr = Xp + (size_t)(32 + c5) * 64 + n * 16 + 8 * h;
            float4 xa = *(const float4*)xr, xb = *(const float4*)(xr + 4);
            U4 u = { pkbf(xa.x, xa.y), pkbf(xa.z, xa.w), pkbf(xb.x, xb.y), pkbf(xb.z, xb.w) };
            t1_1 = __builtin_amdgcn_mfma_f32_32x32x16_bf16(__builtin_bit_cast(s8v, u), bf, t1_1, 0, 0, 0);
        }
    }

    // LDS transpose roundtrip (PROVEN B-frag rebuild)
    #pragma unroll
    for (int tt = 0; tt < 16; ++tt) {
        const int i = (tt & 3) + 8 * (tt >> 2) + 4 * h;
        lds_t1[wv][c5][i]      = t1_0[tt];
        lds_t1[wv][c5][32 + i] = t1_1[tt];
    }
    __syncthreads();

    s8v bfr[4];
    #pragma unroll
    for (int n = 0; n < 4; ++n) {
        const float* p = &lds_t1[wv][c5][n * 16 + 8 * h];
        float4 xa = *(const float4*)p, xb = *(const float4*)(p + 4);
        U4 u = { pkbf(xa.x, xa.y), pkbf(xa.z, xa.w), pkbf(xb.x, xb.y), pkbf(xb.z, xb.w) };
        bfr[n] = __builtin_bit_cast(s8v, u);
    }

    // GEMM2 + epilogue
    #pragma unroll
    for (int At = 0; At < 2; ++At) {
        f16v y = fz;
        #pragma unroll
        for (int n = 0; n < 4; ++n) {
            s8v af = *(const s8v*)(wr + (size_t)(32 * At + c5) * 64 + n * 16 + 8 * h);
            y = __builtin_amdgcn_mfma_f32_32x32x16_bf16(af, bfr[n], y, 0, 0, 0);
        }
        #pragma unroll
        for (int rg = 0; rg < 4; ++rg) {
            float4 bv = *(const float4*)(bt + c * 64 + 32 * At + 8 * rg + 4 * h);
            float be[4] = {bv.x, bv.y, bv.z, bv.w};
            #pragma unroll
            for (int e = 0; e < 4; ++e) {
                const int a = 32 * At + 8 * rg + 4 * h + e;
                const float val = (y[rg * 4 + e] + be[e]) * scale;
                const ushort_t ov = (ushort_t)f2bf(val);
                const size_t base =
                    ((size_t)((bI * HEADS + (a >> 4) * RH + (c >> 4)) * TT + t)) * 256;
                if (proj == 0)      q_bf[base + (a & 15) * 16 + (c & 15)] = ov;
                else if (proj == 1) k_bf[base + (a & 15) * 16 + (c & 15)] = ov;
                else                vt_bf[base + (c & 15) * 16 + (a & 15)] = ov;
            }
        }
    }
}

// ---------------------------------------------------------------------------
// MFMA out-projection, hi/lo split (3 products) on both GEMMs; B-frag rebuild
// via the PROVEN LDS roundtrip. 1 wave per (token, col-half), 96 blocks.
// ---------------------------------------------------------------------------
__global__ __launch_bounds__(256) void pdense_out_mfma2(
    const float* __restrict__ att,
    const ushort_t* __restrict__ woct_h, const ushort_t* __restrict__ woct_l,
    const ushort_t* __restrict__ wort_h, const ushort_t* __restrict__ wort_l,
    const float* __restrict__ boT, float* __restrict__ out)
{
    __shared__ float lds_t1[4][32][68];

    const int wv = threadIdx.x >> 6;
    const int task = blockIdx.x * 4 + wv;            // 0..383
    const int token = task >> 1, ch = task & 1;
    const int lane = threadIdx.x & 63;
    const int c5 = lane & 31, h = lane >> 5;
    const int c = ch * 32 + c5;

    const float* Xp = att + (size_t)token * 4096;
    const f16v fz = {0,0,0,0,0,0,0,0,0,0,0,0,0,0,0,0};

    // GEMM1: T1 = att @ Wo_col (A = att rows hi/lo, B = woct hi/lo)
    f16v t1_0 = fz, t1_1 = fz;
    #pragma unroll
    for (int n = 0; n < 4; ++n) {
        s8v bh = *(const s8v*)(woct_h + c * 64 + n * 16 + 8 * h);
        s8v bl = *(const s8v*)(woct_l + c * 64 + n * 16 + 8 * h);
        #pragma unroll
        for (int T = 0; T < 2; ++T) {
            const float* xr = Xp + (size_t)(32 * T + c5) * 64 + n * 16 + 8 * h;
            float4 xa = *(const float4*)xr, xb = *(const float4*)(xr + 4);
            uint32 hw0, lw0, hw1, lw1, hw2, lw2, hw3, lw3;
            hl_pair(xa.x, xa.y, hw0, lw0);
            hl_pair(xa.z, xa.w, hw1, lw1);
            hl_pair(xb.x, xb.y, hw2, lw2);
            hl_pair(xb.z, xb.w, hw3, lw3);
            U4 uh = {hw0, hw1, hw2, hw3}, ul = {lw0, lw1, lw2, lw3};
            s8v ah = __builtin_bit_cast(s8v, uh), al = __builtin_bit_cast(s8v, ul);
            f16v acc = (T == 0) ? t1_0 : t1_1;
            acc = __builtin_amdgcn_mfma_f32_32x32x16_bf16(ah, bh, acc, 0, 0, 0);
            acc = __builtin_amdgcn_mfma_f32_32x32x16_bf16(al, bh, acc, 0, 0, 0);
            acc = __builtin_amdgcn_mfma_f32_32x32x16_bf16(ah, bl, acc, 0, 0, 0);
            if (T == 0) t1_0 = acc; else t1_1 = acc;
        }
    }

    // LDS roundtrip: [c5][i] then read back contiguous, hi/lo split
    #pragma unroll
    for (int tt = 0; tt < 16; ++tt) {
        const int i = (tt & 3) + 8 * (tt >> 2) + 4 * h;
        lds_t1[wv][c5][i]      = t1_0[tt];
        lds_t1[wv][c5][32 + i] = t1_1[tt];
    }
    __syncthreads();

    s8v bfh[4], bfl[4];
    #pragma unroll
    for (int n = 0; n < 4; ++n) {
        const float* p = &lds_t1[wv][c5][n * 16 + 8 * h];
        float4 xa = *(const float4*)p, xb = *(const float4*)(p + 4);
        uint32 h0, l0, h1, l1, h2, l2, h3, l3;
        hl_pair(xa.x, xa.y, h0, l0);
        hl_pair(xa.z, xa.w, h1, l1);
        hl_pair(xb.x, xb.y, h2, l2);
        hl_pair(xb.z, xb.w, h3, l3);
        U4 uh = {h0, h1, h2, h3}, ul = {l0, l1, l2, l3};
        bfh[n] = __builtin_bit_cast(s8v, uh);
        bfl[n] = __builtin_bit_cast(s8v, ul);
    }

    // GEMM2: Y = Wo_row^T @ T1 (A = wort hi/lo) + bias, /h
    #pragma unroll
    for (int At = 0; At < 2; ++At) {
        f16v y = fz;
        #pragma unroll
        for (int n = 0; n < 4; ++n) {
            s8v awh = *(const s8v*)(wort_h + (size_t)(32 * At + c5) * 64 + n * 16 + 8 * h);
            s8v awl = *(const s8v*)(wort_l + (size_t)(32 * At + c5) * 64 + n * 16 + 8 * h);
            y = __builtin_amdgcn_mfma_f32_32x32x16_bf16(awh, bfh[n], y, 0, 0, 0);
            y = __builtin_amdgcn_mfma_f32_32x32x16_bf16(awh, bfl[n], y, 0, 0, 0);
            y = __builtin_amdgcn_mfma_f32_32x32x16_bf16(awl, bfh[n], y, 0, 0, 0);
        }
        #pragma unroll
        for (int rg = 0; rg < 4; ++rg) {
            float4 bv = *(const float4*)(boT + c * 64 + 32 * At + 8 * rg + 4 * h);
            float be[4] = {bv.x, bv.y, bv.z, bv.w};
            #pragma unroll
            for (int e = 0; e < 4; ++e) {
                const int a = 32 * At + 8 * rg + 4 * h + e;
                out[(size_t)token * 4096 + a * 64 + c] = (y[rg * 4 + e] + be[e]) * INV_H;
            }
        }
    }
}

// ---------------------------------------------------------------------------
// MFMA attention v2 (verbatim R10/R13, verified).
// ---------------------------------------------------------------------------
__global__ __launch_bounds__(256, 4) void attn_kernel(
    const ushort_t* __restrict__ q_bf,
    const ushort_t* __restrict__ k_bf,
    const ushort_t* __restrict__ vt_bf,
    float* __restrict__ att)
{
    __shared__ float lds_z[4][64][9];
    __shared__ float lds_pv[4][64][17];

    const int ip = blockIdx.x % (TT / 2);
    const int vh = (blockIdx.x / (TT / 2)) % VHEADS;
    const int bI = blockIdx.x / ((TT / 2) * VHEADS);
    const int l = (vh >= 1) + (vh >= 3) + (vh >= 6);
    const int r = vh - (l * (l + 1)) / 2;
    const int head = l * RH + r;
    const int i0 = ip * 2;
    const int lane = threadIdx.x & 63;
    const int wv = threadIdx.x >> 6;
    const int c5 = lane & 31;
    const int h  = lane >> 5;

    const size_t hb = (size_t)(bI * HEADS + head) * TT * 256;
    const int frow = (c5 & 15) * 16 + 8 * h;

    s8v qf = *(const s8v*)(q_bf + hb + (size_t)(i0 + (c5 >> 4)) * 256 + frow);
    const ushort_t* kb = k_bf + hb + frow;
    const ushort_t* vb = vt_bf + hb + frow;

    const int jb = wv * (TT / 4);
    const f16v fz16 = {0,0,0,0,0,0,0,0,0,0,0,0,0,0,0,0};

    float ls[8] = {0,0,0,0,0,0,0,0};
    #pragma unroll 3
    for (int jp = 0; jp < 12; ++jp) {
        const int j0g = jb + jp * 2;
        s8v kf = *(const s8v*)(kb + (size_t)(j0g + (c5 >> 4)) * 256);
        f16v d = __builtin_amdgcn_mfma_f32_32x32x16_bf16(kf, qf, fz16, 0, 0, 0);
        #pragma unroll
        for (int t = 0; t < 8; ++t)
            ls[t] += exp2f(d[t]) + exp2f(d[t + 8]);
    }
    #pragma unroll
    for (int t = 0; t < 8; ++t) lds_z[wv][lane][t] = ls[t];
    __syncthreads();
    float inv[8];
    #pragma unroll
    for (int t = 0; t < 8; ++t) {
        float s = lds_z[0][lane][t] + lds_z[1][lane][t]
                + lds_z[2][lane][t] + lds_z[3][lane][t];
        inv[t] = 1.f / s;
    }

    f16v pv = fz16;
    #pragma unroll 2
    for (int jp = 0; jp < 12; ++jp) {
        const int j0g = jb + jp * 2;
        s8v kf = *(const s8v*)(kb + (size_t)(j0g + (c5 >> 4)) * 256);
        f16v d = __builtin_amdgcn_mfma_f32_32x32x16_bf16(kf, qf, fz16, 0, 0, 0);
        float w[16];
        #pragma unroll
        for (int t = 0; t < 8; ++t) {
            w[t]     = exp2f(d[t])     * inv[t];
            w[t + 8] = exp2f(d[t + 8]) * inv[t];
        }
        uint32 A0 = pkbf(w[0],  w[1]),  A1 = pkbf(w[2],  w[3]);
        uint32 A2 = pkbf(w[4],  w[5]),  A3 = pkbf(w[6],  w[7]);
        uint32 B0 = pkbf(w[8],  w[9]),  B1 = pkbf(w[10], w[11]);
        uint32 B2 = pkbf(w[12], w[13]), B3 = pkbf(w[14], w[15]);
        hswap(A2, A0, h); hswap(A3, A1, h);
        hswap(B2, B0, h); hswap(B3, B1, h);
        U4 fa = {A0, A1, A2, A3};
        U4 fb = {B0, B1, B2, B3};
        s8v vf0 = *(const s8v*)(vb + (size_t)(j0g + 0) * 256);
        s8v vf1 = *(const s8v*)(vb + (size_t)(j0g + 1) * 256);
        pv = __builtin_amdgcn_mfma_f32_32x32x16_bf16(__builtin_bit_cast(s8v, fa), vf0, pv, 0, 0, 0);
        pv = __builtin_amdgcn_mfma_f32_32x32x16_bf16(__builtin_bit_cast(s8v, fb), vf1, pv, 0, 0, 0);
    }

    #pragma unroll
    for (int t = 0; t < 16; ++t) lds_pv[wv][lane][t] = pv[t];
    __syncthreads();

    if (c5 < 16) {
        #pragma unroll
        for (int rr = 0; rr < 4; ++rr) {
            const int reg = wv * 4 + rr;
            float v = lds_pv[0][lane][reg] + lds_pv[1][lane][reg]
                    + lds_pv[2][lane][reg] + lds_pv[3][lane][reg];
            const int row = rr + 8 * wv + 4 * h;
            const int i = row >> 4, p = row & 15;
            att[((size_t)(bI * TT + i0 + i) * DD + l * 16 + p) * DD + r * 16 + c5] = v;
        }
    }
}

// ---------------------------------------------------------------------------
extern "C" void kernel_launch(void* const* d_in, const int* in_sizes, int n_in,
                              void* d_out, int out_size, void* d_ws, size_t ws_size,
                              hipStream_t stream) {
    const float* queries = (const float*)d_in[0];
    const float* keys    = (const float*)d_in[1];
    const float* values  = (const float*)d_in[2];
    const float* Wq_row  = (const float*)d_in[3];
    const float* Wq_col  = (const float*)d_in[4];
    const float* bq      = (const float*)d_in[5];
    const float* Wk_row  = (const float*)d_in[6];
    const float* Wk_col  = (const float*)d_in[7];
    const float* bk      = (const float*)d_in[8];
    const float* Wv_row  = (const float*)d_in[9];
    const float* Wv_col  = (const float*)d_in[10];
    const float* bv      = (const float*)d_in[11];
    const float* Wo_row  = (const float*)d_in[12];
    const float* Wo_col  = (const float*)d_in[13];
    const float* bo      = (const float*)d_in[14];
    float* out = (float*)d_out;

    const size_t SEP = (size_t)BB * HEADS * TT * 256;   // 786432 elements
    ushort_t* q_bf  = (ushort_t*)d_ws;
    ushort_t* k_bf  = q_bf + SEP;
    ushort_t* vt_bf = k_bf + SEP;
    float*    att   = (float*)(vt_bf + SEP);
    ushort_t* wct    = (ushort_t*)(att + SEP);
    ushort_t* wrt    = wct + 3 * 4096;
    float*    bT     = (float*)(wrt + 3 * 4096);
    ushort_t* woct_h = (ushort_t*)(bT + 3 * 4096);
    ushort_t* woct_l = woct_h + 4096;
    ushort_t* wort_h = woct_l + 4096;
    ushort_t* wort_l = wort_h + 4096;
    float*    boT    = (float*)(wort_l + 4096);

    wprep_kernel<<<12, 256, 0, stream>>>(
        Wq_row, Wq_col, bq, Wk_row, Wk_col, bk, Wv_row, Wv_col, bv,
        Wo_row, Wo_col, bo,
        wct, wrt, bT, woct_h, woct_l, wort_h, wort_l, boT);

    pdense_qkv_mfma<<<QKV_BLOCKS + ZF_BLOCKS, 256, 0, stream>>>(
        queries, keys, values, wct, wrt, bT, q_bf, k_bf, vt_bf, att);

    attn_kernel<<<BB * VHEADS * (TT / 2), 256, 0, stream>>>(q_bf, k_bf, vt_bf, att);

    pdense_out_mfma2<<<NTOK * 2 / 4, 256, 0, stream>>>(
        att, woct_h, woct_l, wort_h, wort_l, boT, out);
}